// Round 1
// baseline (76.296 us; speedup 1.0000x reference)
//
#include <hip/hip_runtime.h>

// DRMM scoring kernel.
// Shapes: B=32, D=8, QL=16, DL=512, E=300, V=50000, 5 histogram bins.
// One block per (b,d) doc pair; 512 threads = 1 thread per doc token.

constexpr int Bn  = 32;
constexpr int Dn  = 8;
constexpr int QLn = 16;
constexpr int DLn = 512;
constexpr int En  = 300;

__global__ __launch_bounds__(512) void drmm_score(
    const int*   __restrict__ bq,    // [B,QL]
    const int*   __restrict__ bd,    // [B,D,DL]
    const float* __restrict__ emb,   // [V,E]
    const float* __restrict__ w_g,   // [E]
    const float* __restrict__ b_g,   // [1]
    const float* __restrict__ w1,    // [5]
    const float* __restrict__ b1,    // [1]
    const float* __restrict__ w2,    // [1]
    const float* __restrict__ b2,    // [1]
    const float* __restrict__ w_o,   // [1]
    const float* __restrict__ b_o,   // [1]
    float*       __restrict__ out)   // [B*D]
{
    __shared__ __attribute__((aligned(16))) float q_lds[QLn * En]; // 19200 B
    __shared__ float pn_s[QLn][17];
    __shared__ float pg_s[QLn][17];
    __shared__ float qn_s[QLn];
    __shared__ float gate_s[QLn];
    __shared__ float tw_s[QLn];
    __shared__ unsigned long long hist_s[QLn]; // 5 x 12-bit packed counters per q
    __shared__ float wsum_s[QLn];

    const int n   = blockIdx.x;   // 0..255  (b*8 + d)
    const int b   = n >> 3;
    const int tid = threadIdx.x;  // 0..511

    // ---- Phase 1: stage query embeddings into LDS ----
    for (int idx = tid; idx < QLn * En; idx += 512) {
        const int  q   = idx / En;
        const int  e   = idx - q * En;
        const long tok = bq[b * QLn + q];
        q_lds[idx] = emb[tok * (long)En + e];
    }
    if (tid < QLn) hist_s[tid] = 0ull;
    __syncthreads();

    // ---- Phase 2: query norms + gate logits (16 threads per q) ----
    if (tid < 256) {
        const int q = tid >> 4, j = tid & 15;
        float pn = 0.f, pg = 0.f;
        for (int e = j; e < En; e += 16) {
            const float v = q_lds[q * En + e];
            pn = fmaf(v, v, pn);
            pg = fmaf(v, w_g[e], pg);
        }
        pn_s[q][j] = pn;
        pg_s[q][j] = pg;
    }
    __syncthreads();
    if (tid < QLn) {
        float sn = 0.f, sg = 0.f;
        for (int j = 0; j < 16; ++j) { sn += pn_s[tid][j]; sg += pg_s[tid][j]; }
        qn_s[tid]   = sqrtf(sn);
        gate_s[tid] = sg + b_g[0];
    }
    __syncthreads();
    if (tid == 0) {
        // softmax over the 16 query terms
        float m = gate_s[0];
        for (int q = 1; q < QLn; ++q) m = fmaxf(m, gate_s[q]);
        float ex[QLn];
        float s = 0.f;
        for (int q = 0; q < QLn; ++q) { ex[q] = expf(gate_s[q] - m); s += ex[q]; }
        for (int q = 0; q < QLn; ++q) tw_s[q] = ex[q] / s;
    }
    __syncthreads();

    // ---- Phase 3: per-token cosine sims vs all 16 query terms ----
    const long tok = bd[n * DLn + tid];
    const float* __restrict__ drow = emb + tok * (long)En;

    float acc[QLn];
#pragma unroll
    for (int q = 0; q < QLn; ++q) acc[q] = 0.f;
    float nrm = 0.f;

    for (int e = 0; e < En; e += 4) {
        const float4 dv = *reinterpret_cast<const float4*>(drow + e);
        nrm = fmaf(dv.x, dv.x, nrm);
        nrm = fmaf(dv.y, dv.y, nrm);
        nrm = fmaf(dv.z, dv.z, nrm);
        nrm = fmaf(dv.w, dv.w, nrm);
#pragma unroll
        for (int q = 0; q < QLn; ++q) {
            const float4 qv = *reinterpret_cast<const float4*>(&q_lds[q * En + e]);
            float a = acc[q];
            a = fmaf(dv.x, qv.x, a);
            a = fmaf(dv.y, qv.y, a);
            a = fmaf(dv.z, qv.z, a);
            a = fmaf(dv.w, qv.w, a);
            acc[q] = a;
        }
    }

    const float dn = sqrtf(nrm);
    unsigned long long cnt[QLn];
#pragma unroll
    for (int q = 0; q < QLn; ++q) {
        const float denom = fmaxf(qn_s[q] * dn, 1e-8f);
        const float c     = acc[q] / denom;
        // numpy.histogram semantics with edges [-1,-0.5,0,0.5,1,1]:
        // first 4 bins half-open [lo,hi), last bin closed [1.0,1.0].
        int bin = -1;
        if      (c >= -1.0f && c < -0.5f) bin = 0;
        else if (c >= -0.5f && c <  0.0f) bin = 1;
        else if (c >=  0.0f && c <  0.5f) bin = 2;
        else if (c >=  0.5f && c <  1.0f) bin = 3;
        else if (c ==  1.0f)              bin = 4;
        cnt[q] = (bin >= 0) ? (1ull << (12 * bin)) : 0ull;
    }

    // wave reduce the packed counters, then one LDS atomic per wave per q
    const int lane = tid & 63;
#pragma unroll
    for (int q = 0; q < QLn; ++q) {
        unsigned long long v = cnt[q];
        for (int off = 32; off > 0; off >>= 1) v += __shfl_down(v, off, 64);
        if (lane == 0) atomicAdd(&hist_s[q], v);
    }
    __syncthreads();

    // ---- Phase 4: ffnn + gated sum -> score ----
    if (tid < QLn) {
        const unsigned long long h = hist_s[tid];
        float f = 0.f;
        f = fmaf((float)((h >>  0) & 0xFFFull), w1[0], f);
        f = fmaf((float)((h >> 12) & 0xFFFull), w1[1], f);
        f = fmaf((float)((h >> 24) & 0xFFFull), w1[2], f);
        f = fmaf((float)((h >> 36) & 0xFFFull), w1[3], f);
        f = fmaf((float)((h >> 48) & 0xFFFull), w1[4], f);
        f += b1[0];
        f = f * w2[0] + b2[0];
        wsum_s[tid] = f * tw_s[tid];
    }
    __syncthreads();
    if (tid == 0) {
        float s = 0.f;
        for (int q = 0; q < QLn; ++q) s += wsum_s[q];
        out[n] = s * w_o[0] + b_o[0];
    }
}

extern "C" void kernel_launch(void* const* d_in, const int* in_sizes, int n_in,
                              void* d_out, int out_size, void* d_ws, size_t ws_size,
                              hipStream_t stream) {
    const int*   bq  = (const int*)  d_in[0];  // batch_queries
    // d_in[1] query_len: unused by reference
    const int*   bd  = (const int*)  d_in[2];  // batch_docs
    // d_in[3] doc_len: unused by reference
    const float* emb = (const float*)d_in[4];
    const float* w_g = (const float*)d_in[5];
    const float* b_g = (const float*)d_in[6];
    const float* w1  = (const float*)d_in[7];
    const float* b1  = (const float*)d_in[8];
    const float* w2  = (const float*)d_in[9];
    const float* b2  = (const float*)d_in[10];
    const float* w_o = (const float*)d_in[11];
    const float* b_o = (const float*)d_in[12];

    drmm_score<<<Bn * Dn, 512, 0, stream>>>(
        bq, bd, emb, w_g, b_g, w1, b1, w2, b2, w_o, b_o, (float*)d_out);
}

// Round 2
// 70.777 us; speedup vs baseline: 1.0780x; 1.0780x over previous
//
#include <hip/hip_runtime.h>

// DRMM scoring kernel, round 2.
// Shapes: B=32, D=8, QL=16, DL=512, E=300, V=50000, 5 histogram bins.
// One block per (b,d) doc pair; 256 threads, T=2 doc tokens per lane.
// Per-token dot/norm summation order kept bit-identical to round-1 (passing).

constexpr int Bn  = 32;
constexpr int Dn  = 8;
constexpr int QLn = 16;
constexpr int DLn = 512;
constexpr int En  = 300;

__global__ __launch_bounds__(256) void drmm_score(
    const int*   __restrict__ bq,    // [B,QL]
    const int*   __restrict__ bd,    // [B,D,DL]
    const float* __restrict__ emb,   // [V,E]
    const float* __restrict__ w_g,   // [E]
    const float* __restrict__ b_g,   // [1]
    const float* __restrict__ w1,    // [5]
    const float* __restrict__ b1,    // [1]
    const float* __restrict__ w2,    // [1]
    const float* __restrict__ b2,    // [1]
    const float* __restrict__ w_o,   // [1]
    const float* __restrict__ b_o,   // [1]
    float*       __restrict__ out)   // [B*D]
{
    __shared__ __attribute__((aligned(16))) float q_lds[QLn * En]; // 19200 B
    __shared__ float pn_s[QLn][17];
    __shared__ float pg_s[QLn][17];
    __shared__ float qn_s[QLn];
    __shared__ float gate_s[QLn];
    __shared__ float tw_s[QLn];
    __shared__ unsigned long long hist_s[QLn]; // 5 x 12-bit packed counters per q
    __shared__ float wsum_s[QLn];

    const int n   = blockIdx.x;   // 0..255  (b*8 + d)
    const int b   = n >> 3;
    const int tid = threadIdx.x;  // 0..255

    // ---- Phase 1: stage query embeddings into LDS ----
    for (int idx = tid; idx < QLn * En; idx += 256) {
        const int  q   = idx / En;
        const int  e   = idx - q * En;
        const long tok = bq[b * QLn + q];
        q_lds[idx] = emb[tok * (long)En + e];
    }
    if (tid < QLn) hist_s[tid] = 0ull;
    __syncthreads();

    // ---- Phase 2: query norms + gate logits (16 threads per q) ----
    {
        const int q = tid >> 4, j = tid & 15;
        float pn = 0.f, pg = 0.f;
        for (int e = j; e < En; e += 16) {
            const float v = q_lds[q * En + e];
            pn = fmaf(v, v, pn);
            pg = fmaf(v, w_g[e], pg);
        }
        pn_s[q][j] = pn;
        pg_s[q][j] = pg;
    }
    __syncthreads();
    if (tid < QLn) {
        float sn = 0.f, sg = 0.f;
        for (int j = 0; j < 16; ++j) { sn += pn_s[tid][j]; sg += pg_s[tid][j]; }
        qn_s[tid]   = sqrtf(sn);
        gate_s[tid] = sg + b_g[0];
    }
    __syncthreads();
    if (tid == 0) {
        float m = gate_s[0];
        for (int q = 1; q < QLn; ++q) m = fmaxf(m, gate_s[q]);
        float ex[QLn];
        float s = 0.f;
        for (int q = 0; q < QLn; ++q) { ex[q] = expf(gate_s[q] - m); s += ex[q]; }
        for (int q = 0; q < QLn; ++q) tw_s[q] = ex[q] / s;
    }
    __syncthreads();

    // ---- Phase 3: per-token cosine sims; 2 tokens per lane ----
    const long tok0 = bd[n * DLn + tid];
    const long tok1 = bd[n * DLn + tid + 256];
    const float* __restrict__ r0 = emb + tok0 * (long)En;
    const float* __restrict__ r1 = emb + tok1 * (long)En;

    float acc0[QLn], acc1[QLn];
#pragma unroll
    for (int q = 0; q < QLn; ++q) { acc0[q] = 0.f; acc1[q] = 0.f; }
    float nr0 = 0.f, nr1 = 0.f;

    // depth-2 register prefetch of the scattered doc-row float4s
    float4 a0 = *reinterpret_cast<const float4*>(r0 + 0);
    float4 a1 = *reinterpret_cast<const float4*>(r1 + 0);
    float4 b0f = *reinterpret_cast<const float4*>(r0 + 4);
    float4 b1f = *reinterpret_cast<const float4*>(r1 + 4);

#define DRMM_COMPUTE(d0, d1, EE)                                          \
    do {                                                                  \
        nr0 = fmaf((d0).x, (d0).x, nr0);                                  \
        nr0 = fmaf((d0).y, (d0).y, nr0);                                  \
        nr0 = fmaf((d0).z, (d0).z, nr0);                                  \
        nr0 = fmaf((d0).w, (d0).w, nr0);                                  \
        nr1 = fmaf((d1).x, (d1).x, nr1);                                  \
        nr1 = fmaf((d1).y, (d1).y, nr1);                                  \
        nr1 = fmaf((d1).z, (d1).z, nr1);                                  \
        nr1 = fmaf((d1).w, (d1).w, nr1);                                  \
        _Pragma("unroll")                                                 \
        for (int q = 0; q < QLn; ++q) {                                   \
            const float4 qv =                                             \
                *reinterpret_cast<const float4*>(&q_lds[q * En + (EE)]);  \
            float s0 = acc0[q];                                           \
            s0 = fmaf((d0).x, qv.x, s0);                                  \
            s0 = fmaf((d0).y, qv.y, s0);                                  \
            s0 = fmaf((d0).z, qv.z, s0);                                  \
            s0 = fmaf((d0).w, qv.w, s0);                                  \
            acc0[q] = s0;                                                 \
            float s1 = acc1[q];                                           \
            s1 = fmaf((d1).x, qv.x, s1);                                  \
            s1 = fmaf((d1).y, qv.y, s1);                                  \
            s1 = fmaf((d1).z, qv.z, s1);                                  \
            s1 = fmaf((d1).w, qv.w, s1);                                  \
            acc1[q] = s1;                                                 \
        }                                                                 \
    } while (0)

    int e = 0;
    for (; e < En - 8; e += 4) {   // e = 0..288, loads e+8 <= 296
        const float4 c0 = *reinterpret_cast<const float4*>(r0 + e + 8);
        const float4 c1 = *reinterpret_cast<const float4*>(r1 + e + 8);
        DRMM_COMPUTE(a0, a1, e);
        a0 = b0f; a1 = b1f;
        b0f = c0; b1f = c1;
    }
    DRMM_COMPUTE(a0, a1, 292);
    DRMM_COMPUTE(b0f, b1f, 296);
#undef DRMM_COMPUTE

    const float dn0 = sqrtf(nr0);
    const float dn1 = sqrtf(nr1);

    unsigned long long cnt[QLn];
#pragma unroll
    for (int q = 0; q < QLn; ++q) {
        unsigned long long v = 0ull;
        {
            const float denom = fmaxf(qn_s[q] * dn0, 1e-8f);
            const float c     = acc0[q] / denom;
            int bin = -1;
            if      (c >= -1.0f && c < -0.5f) bin = 0;
            else if (c >= -0.5f && c <  0.0f) bin = 1;
            else if (c >=  0.0f && c <  0.5f) bin = 2;
            else if (c >=  0.5f && c <  1.0f) bin = 3;
            else if (c ==  1.0f)              bin = 4;
            if (bin >= 0) v += 1ull << (12 * bin);
        }
        {
            const float denom = fmaxf(qn_s[q] * dn1, 1e-8f);
            const float c     = acc1[q] / denom;
            int bin = -1;
            if      (c >= -1.0f && c < -0.5f) bin = 0;
            else if (c >= -0.5f && c <  0.0f) bin = 1;
            else if (c >=  0.0f && c <  0.5f) bin = 2;
            else if (c >=  0.5f && c <  1.0f) bin = 3;
            else if (c ==  1.0f)              bin = 4;
            if (bin >= 0) v += 1ull << (12 * bin);
        }
        cnt[q] = v;
    }

    const int lane = tid & 63;
#pragma unroll
    for (int q = 0; q < QLn; ++q) {
        unsigned long long v = cnt[q];
        for (int off = 32; off > 0; off >>= 1) v += __shfl_down(v, off, 64);
        if (lane == 0) atomicAdd(&hist_s[q], v);
    }
    __syncthreads();

    // ---- Phase 4: ffnn + gated sum -> score ----
    if (tid < QLn) {
        const unsigned long long h = hist_s[tid];
        float f = 0.f;
        f = fmaf((float)((h >>  0) & 0xFFFull), w1[0], f);
        f = fmaf((float)((h >> 12) & 0xFFFull), w1[1], f);
        f = fmaf((float)((h >> 24) & 0xFFFull), w1[2], f);
        f = fmaf((float)((h >> 36) & 0xFFFull), w1[3], f);
        f = fmaf((float)((h >> 48) & 0xFFFull), w1[4], f);
        f += b1[0];
        f = f * w2[0] + b2[0];
        wsum_s[tid] = f * tw_s[tid];
    }
    __syncthreads();
    if (tid == 0) {
        float s = 0.f;
        for (int q = 0; q < QLn; ++q) s += wsum_s[q];
        out[n] = s * w_o[0] + b_o[0];
    }
}

extern "C" void kernel_launch(void* const* d_in, const int* in_sizes, int n_in,
                              void* d_out, int out_size, void* d_ws, size_t ws_size,
                              hipStream_t stream) {
    const int*   bq  = (const int*)  d_in[0];  // batch_queries
    // d_in[1] query_len: unused by reference
    const int*   bd  = (const int*)  d_in[2];  // batch_docs
    // d_in[3] doc_len: unused by reference
    const float* emb = (const float*)d_in[4];
    const float* w_g = (const float*)d_in[5];
    const float* b_g = (const float*)d_in[6];
    const float* w1  = (const float*)d_in[7];
    const float* b1  = (const float*)d_in[8];
    const float* w2  = (const float*)d_in[9];
    const float* b2  = (const float*)d_in[10];
    const float* w_o = (const float*)d_in[11];
    const float* b_o = (const float*)d_in[12];

    drmm_score<<<Bn * Dn, 256, 0, stream>>>(
        bq, bd, emb, w_g, b_g, w1, b1, w2, b2, w_o, b_o, (float*)d_out);
}